// Round 7
// baseline (116.945 us; speedup 1.0000x reference)
//
#include <hip/hip_runtime.h>
#include <stdint.h>

// Encoder: B=2,E=512,T=2048,H=8,dh=64, local window |i-j|<=64
// R7: occupancy/balance round.
//     QKV: 128x128x384blk (1.5 blk/CU, imbalanced) -> 64x128x768blk (3/CU even,
//          12 waves/CU = m97 sweet spot).
//     Out: 64x128x256blk (1/CU, 4 waves) -> 64x64x512blk (2/CU, 8 waves).
//     Attention unchanged (control).

#define DEVI __device__ __forceinline__

typedef __attribute__((ext_vector_type(8))) short bf16x8;   // 8 bf16 in 4 VGPRs
typedef __attribute__((ext_vector_type(4))) float f32x4;

DEVI unsigned short f2bf(float f) {               // RNE float->bf16
  unsigned u = __float_as_uint(f);
  u += 0x7fffu + ((u >> 16) & 1u);
  return (unsigned short)(u >> 16);
}
DEVI float bf2f(unsigned short h) { return __uint_as_float(((unsigned)h) << 16); }

#define GLL16(gp, lp)                                                          \
  __builtin_amdgcn_global_load_lds(                                            \
      (const __attribute__((address_space(1))) void*)(gp),                     \
      (__attribute__((address_space(3))) void*)(lp), 16, 0, 0)

#define MFMA(a, b, c) __builtin_amdgcn_mfma_f32_16x16x32_bf16((a), (b), (c), 0, 0, 0)

// ---------------------------------------------------------------------------
// K0: blockIdx.y<16: x[B,E,T] fp32 -> xT[B*T,512] bf16 (transpose)
//     blockIdx.y==16: w_in/w_out fp32 -> bf16 hi (128 rider blocks)
__global__ __launch_bounds__(256) void k_prep(
    const float* __restrict__ x, const float* __restrict__ w_in,
    const float* __restrict__ w_out, unsigned short* __restrict__ xh,
    unsigned short* __restrict__ wih, unsigned short* __restrict__ woh) {
  const int tid = threadIdx.x;
  if (blockIdx.y == 16) {  // weight convert rider: 128 blocks x 8192 elems
    int cb = (blockIdx.z << 6) | blockIdx.x;
    const float* src;
    unsigned short* dst;
    int base;
    if (cb < 96) {        // 96*8192 = 786432 = w_in exactly
      src = w_in; dst = wih; base = cb * 8192;
    } else {              // 32*8192 = 262144 = w_out exactly
      src = w_out; dst = woh; base = (cb - 96) * 8192;
    }
#pragma unroll
    for (int k = 0; k < 8; k++) {
      int idx = base + (k * 256 + tid) * 4;
      float4 v = *(const float4*)&src[idx];
      ushort4 o;
      o.x = f2bf(v.x); o.y = f2bf(v.y); o.z = f2bf(v.z); o.w = f2bf(v.w);
      *(ushort4*)&dst[idx] = o;
    }
    return;
  }
  __shared__ float tile[32][33];
  const int b = blockIdx.z, e0 = blockIdx.y * 32, t0 = blockIdx.x * 32;
  const int j = tid & 31, i = tid >> 5;  // i: 0..7
#pragma unroll
  for (int rr = 0; rr < 4; rr++) {
    int e = e0 + i + rr * 8;
    tile[i + rr * 8][j] = x[((size_t)b * 512 + e) * 2048 + t0 + j];  // coalesced t
  }
  __syncthreads();
#pragma unroll
  for (int rr = 0; rr < 4; rr++) {
    int t = t0 + i + rr * 8;
    float v = tile[j][i + rr * 8];
    size_t o = ((size_t)b * 2048 + t) * 512 + e0 + j;  // coalesced e
    xh[o] = f2bf(v);
  }
}

// ---------------------------------------------------------------------------
// QKV GEMM: C[m,n] = sum_k Ah[m,k]*Bh[n,k] + bias[n], 64x128 tile, BK=32.
// Grid: 768 linear (3 blocks/CU even), XCD-swizzled: 96/XCD = 8m x 12n slab.
// Epilogue: Q(*0.125)/K -> [B,H,T,64] bf16, V -> transposed [B,H,64,T] bf16.
__global__ __launch_bounds__(256) void k_gemm_qkv(
    const unsigned short* __restrict__ Ahg, const unsigned short* __restrict__ Bhg,
    const float* __restrict__ bias, unsigned short* __restrict__ Qs,
    unsigned short* __restrict__ Kks, unsigned short* __restrict__ VvT) {
  const int KD = 512;
  __shared__ __align__(16) unsigned short Ah_s[64 * 32];
  __shared__ __align__(16) unsigned short Bh_s[128 * 32];
  const int tid = threadIdx.x, lane = tid & 63, w = tid >> 6;
  const int bid = blockIdx.x;
  const int xcd = bid & 7, j5 = bid >> 3;              // j5: 0..95
  const int m0 = (xcd * 8 + j5 / 12) * 64, n0 = (j5 % 12) * 128;
  const int wm = (w >> 1) * 32, wn = (w & 1) * 64;     // wave tile 32x64

  f32x4 acc[2][4];
#pragma unroll
  for (int i = 0; i < 2; i++)
#pragma unroll
    for (int j = 0; j < 4; j++) acc[i][j] = (f32x4){0.f, 0.f, 0.f, 0.f};

  const int srw = lane >> 2, sc = (lane & 3) * 8;
  const size_t a0 = (size_t)(m0 + w * 16 + srw) * KD + sc;
  unsigned short* lAh0 = &Ah_s[(w * 16) * 32];
  const size_t b0 = (size_t)(n0 + w * 32 + srw) * KD + sc;
  const size_t b1 = b0 + (size_t)16 * KD;
  unsigned short* lB0 = &Bh_s[(w * 32) * 32];
  unsigned short* lB1 = &Bh_s[(w * 32 + 16) * 32];

  const int fm = lane & 15, fq = (lane >> 4) * 8;

  for (int k0 = 0; k0 < KD; k0 += 32) {
    __syncthreads();
    GLL16(Ahg + a0 + k0, lAh0);
    GLL16(Bhg + b0 + k0, lB0);
    GLL16(Bhg + b1 + k0, lB1);
    __builtin_amdgcn_s_waitcnt(0);
    __syncthreads();

    bf16x8 ah[2], bh[4];
#pragma unroll
    for (int i = 0; i < 2; i++)
      ah[i] = *(const bf16x8*)&Ah_s[(wm + i * 16 + fm) * 32 + fq];
#pragma unroll
    for (int j = 0; j < 4; j++)
      bh[j] = *(const bf16x8*)&Bh_s[(wn + j * 16 + fm) * 32 + fq];
#pragma unroll
    for (int i = 0; i < 2; i++)
#pragma unroll
      for (int j = 0; j < 4; j++)
        acc[i][j] = MFMA(ah[i], bh[j], acc[i][j]);
  }

  // epilogue: C/D layout col=lane&15, row=quad*4+r  [m89-verified]
  const int quad = lane >> 4;
#pragma unroll
  for (int i = 0; i < 2; i++)
#pragma unroll
    for (int j = 0; j < 4; j++) {
      int gn = n0 + wn + j * 16 + fm;
      float bv = bias[gn];
      int sec = gn >> 9, cc = gn & 511;
      int h = cc >> 6, d = cc & 63;
      int gm0 = m0 + wm + i * 16 + quad * 4;       // 4-aligned t base
      int bb = gm0 >> 11, t = gm0 & 2047;
      if (sec == 2) {  // V^T [B,H,64,2048]: 4 consecutive t -> one 8B store
        ushort4 pk;
        pk.x = f2bf(acc[i][j][0] + bv);
        pk.y = f2bf(acc[i][j][1] + bv);
        pk.z = f2bf(acc[i][j][2] + bv);
        pk.w = f2bf(acc[i][j][3] + bv);
        *(ushort4*)&VvT[(((size_t)(bb * 8 + h)) * 64 + d) * 2048 + t] = pk;
      } else {
        unsigned short* dst = sec == 0 ? Qs : Kks;
        float mul = sec == 0 ? 0.125f : 1.0f;  // 1/sqrt(64), exact
#pragma unroll
        for (int r = 0; r < 4; r++) {
          float v = (acc[i][j][r] + bv) * mul;
          dst[(((size_t)(bb * 8 + h)) * 2048 + t + r) * 64 + d] = f2bf(v);
        }
      }
    }
}

// ---------------------------------------------------------------------------
// Out-proj GEMM fused with final transpose * x + relu. Single-pass bf16.
// C[m,n] = sum_k Ah[m,k]*Bh[n,k] + bias[n]; tile 64m x 64n, grid 512 (2/CU).
// XCD-swizzled: 64/XCD = 8m x 8n slab.
// Epilogue: LDS transpose -> out[b,e,t] = relu(C[b,t,e] * x[b,e,t]).
__global__ __launch_bounds__(256) void k_gemm_out(
    const unsigned short* __restrict__ Ahg, const unsigned short* __restrict__ Bhg,
    const float* __restrict__ bias, const float* __restrict__ x,
    float* __restrict__ out) {
  const int KD = 512;
  __shared__ __align__(16) union {
    struct {
      unsigned short Ah[64 * 32];
      unsigned short Bh[64 * 32];
    } st;                       // 8 KB staging
    float tile[64][65];         // 16.6 KB epilogue transpose
  } u;
  const int tid = threadIdx.x, lane = tid & 63, w = tid >> 6;
  const int bid = blockIdx.x;
  const int xcd = bid & 7, j5 = bid >> 3;              // j5: 0..63
  const int m0 = (xcd * 8 + (j5 >> 3)) * 64, n0 = (j5 & 7) * 64;
  const int wm = (w >> 1) * 32, wn = (w & 1) * 32;     // wave tile 32x32

  f32x4 acc[2][2];
#pragma unroll
  for (int i = 0; i < 2; i++)
#pragma unroll
    for (int j = 0; j < 2; j++) acc[i][j] = (f32x4){0.f, 0.f, 0.f, 0.f};

  const int srw = lane >> 2, sc = (lane & 3) * 8;
  const size_t a0 = (size_t)(m0 + w * 16 + srw) * KD + sc;
  const size_t b0 = (size_t)(n0 + w * 16 + srw) * KD + sc;
  unsigned short* lAh0 = &u.st.Ah[(w * 16) * 32];
  unsigned short* lB0 = &u.st.Bh[(w * 16) * 32];

  const int fm = lane & 15, fq = (lane >> 4) * 8;

  for (int k0 = 0; k0 < KD; k0 += 32) {
    __syncthreads();
    GLL16(Ahg + a0 + k0, lAh0);
    GLL16(Bhg + b0 + k0, lB0);
    __builtin_amdgcn_s_waitcnt(0);
    __syncthreads();

    bf16x8 ah[2], bh[2];
#pragma unroll
    for (int i = 0; i < 2; i++) {
      ah[i] = *(const bf16x8*)&u.st.Ah[(wm + i * 16 + fm) * 32 + fq];
      bh[i] = *(const bf16x8*)&u.st.Bh[(wn + i * 16 + fm) * 32 + fq];
    }
#pragma unroll
    for (int i = 0; i < 2; i++)
#pragma unroll
      for (int j = 0; j < 2; j++)
        acc[i][j] = MFMA(ah[i], bh[j], acc[i][j]);
  }

  __syncthreads();  // all frag reads done before tile overwrites staging
  // write acc+bias into transpose tile: tile[t_local][e_local]
  const int quad = lane >> 4;
#pragma unroll
  for (int i = 0; i < 2; i++)
#pragma unroll
    for (int j = 0; j < 2; j++) {
      int ln = wn + j * 16 + fm;
      float bv = bias[n0 + ln];
#pragma unroll
      for (int r = 0; r < 4; r++) {
        int lm = wm + i * 16 + quad * 4 + r;
        u.tile[lm][ln] = acc[i][j][r] + bv;
      }
    }
  __syncthreads();

  // out[b,e,t] = relu(tile[t][e] * x[b,e,t]); coalesced along t (64x4B rows)
  const int bb = m0 >> 11, t0 = m0 & 2047;
  const int tt = tid & 63, e0w = tid >> 6;
#pragma unroll
  for (int k = 0; k < 16; k++) {
    int ee = e0w + k * 4;
    size_t o = ((size_t)bb * 512 + n0 + ee) * 2048 + t0 + tt;
    float v = u.tile[tt][ee] * x[o];
    out[o] = fmaxf(v, 0.f);
  }
}

// ---------------------------------------------------------------------------
// K2: local attention. Block = (b,h, 64 queries). Window = 192 keys.
// V arrives already transposed in global [B,H,64,2048].
#define KSTR 88   // K_lds row stride (bf16): 176B, 2-way-free b128 reads
#define VSTR 216  // Vt/P row stride (bf16): 432B, 2-way-free b128 reads
__global__ __launch_bounds__(256) void k_attention(
    const unsigned short* __restrict__ Qs, const unsigned short* __restrict__ Kks,
    const unsigned short* __restrict__ VvT, unsigned short* __restrict__ ctx_hi) {
  __shared__ __align__(16) unsigned short KP_s[192 * KSTR];  // K, later P (64 x VSTR)
  __shared__ __align__(16) unsigned short Vt_s[64 * VSTR];   // V^T [dh][key]
  __shared__ float redm[4 * 64];
  __shared__ float reds[4 * 64];

  const int tid = threadIdx.x, lane = tid & 63, w = tid >> 6;
  const int q0 = blockIdx.x * 64;
  const int bh = blockIdx.y;
  const int j0 = q0 - 64;
  const size_t base = (size_t)bh * 2048 * 64;

  // stage K rows (clamped; garbage rows are masked before softmax)
  for (int idx = tid; idx < 192 * 8; idx += 256) {
    int r = idx >> 3, c = idx & 7;
    int j = j0 + r;
    j = j < 0 ? 0 : (j > 2047 ? 2047 : j);
    uint4 v = *(const uint4*)&Kks[base + (size_t)j * 64 + c * 8];
    *(uint4*)&KP_s[r * KSTR + c * 8] = v;
  }
  // stage V^T rows: pure uint4 copies (j0 and chunk starts 8-aligned -> a
  // chunk is never OOB-straddling; OOB chunks fully zero)
  for (int idx = tid; idx < 64 * 24; idx += 256) {
    int d = idx / 24, c8 = (idx % 24) * 8;
    int j = j0 + c8;
    uint4 v;
    if (j >= 0 && j < 2048)
      v = *(const uint4*)&VvT[base + (size_t)d * 2048 + j];
    else
      v = (uint4){0u, 0u, 0u, 0u};  // OOB keys ZERO (0*garbage hazard)
    *(uint4*)&Vt_s[d * VSTR + c8] = v;
  }

  // Q fragments straight from global (A layout: m=lane&15, k=quad*8+j)
  const int fm = lane & 15, quad = lane >> 4;
  bf16x8 aq[4][2];
#pragma unroll
  for (int mt = 0; mt < 4; mt++)
#pragma unroll
    for (int ks = 0; ks < 2; ks++)
      aq[mt][ks] = *(const bf16x8*)&Qs[base + (size_t)(q0 + mt * 16 + fm) * 64 +
                                       ks * 32 + quad * 8];
  __syncthreads();

  // S = Qs @ K^T ; wave covers key-cols [w*48, w*48+48)
  const int n0s = w * 48;
  f32x4 s_acc[4][3];
#pragma unroll
  for (int mt = 0; mt < 4; mt++)
#pragma unroll
    for (int nt = 0; nt < 3; nt++) s_acc[mt][nt] = (f32x4){0.f, 0.f, 0.f, 0.f};
#pragma unroll
  for (int nt = 0; nt < 3; nt++)
#pragma unroll
    for (int ks = 0; ks < 2; ks++) {
      bf16x8 bk =
          *(const bf16x8*)&KP_s[(n0s + nt * 16 + fm) * KSTR + ks * 32 + quad * 8];
#pragma unroll
      for (int mt = 0; mt < 4; mt++) s_acc[mt][nt] = MFMA(aq[mt][ks], bk, s_acc[mt][nt]);
    }

  // mask (REPLACE, not add) + per-row max
  float rm[4][4];
#pragma unroll
  for (int mt = 0; mt < 4; mt++)
#pragma unroll
    for (int r = 0; r < 4; r++) rm[mt][r] = -1e30f;
#pragma unroll
  for (int mt = 0; mt < 4; mt++)
#pragma unroll
    for (int nt = 0; nt < 3; nt++) {
      int jj = n0s + nt * 16 + fm;
      int jg = j0 + jj;
#pragma unroll
      for (int r = 0; r < 4; r++) {
        int ii = mt * 16 + quad * 4 + r;
        bool ok = (jj >= ii) && (jj <= ii + 128) && (jg >= 0) && (jg < 2048);
        float sv = ok ? s_acc[mt][nt][r] : -1e30f;
        s_acc[mt][nt][r] = sv;
        rm[mt][r] = fmaxf(rm[mt][r], sv);
      }
    }
  // reduce max over the 16-lane col group, then cross-wave via LDS
#pragma unroll
  for (int off = 1; off < 16; off <<= 1)
#pragma unroll
    for (int mt = 0; mt < 4; mt++)
#pragma unroll
      for (int r = 0; r < 4; r++)
        rm[mt][r] = fmaxf(rm[mt][r], __shfl_xor(rm[mt][r], off));
  if (fm == 0)
#pragma unroll
    for (int mt = 0; mt < 4; mt++)
#pragma unroll
      for (int r = 0; r < 4; r++)
        redm[w * 64 + mt * 16 + quad * 4 + r] = rm[mt][r];
  __syncthreads();
  float fmx[4][4];
#pragma unroll
  for (int mt = 0; mt < 4; mt++)
#pragma unroll
    for (int r = 0; r < 4; r++) {
      int row = mt * 16 + quad * 4 + r;
      fmx[mt][r] = fmaxf(fmaxf(redm[row], redm[64 + row]),
                         fmaxf(redm[128 + row], redm[192 + row]));
    }
  // exp + row sum (masked entries underflow to exactly 0)
  float rs[4][4];
#pragma unroll
  for (int mt = 0; mt < 4; mt++)
#pragma unroll
    for (int r = 0; r < 4; r++) rs[mt][r] = 0.f;
#pragma unroll
  for (int mt = 0; mt < 4; mt++)
#pragma unroll
    for (int nt = 0; nt < 3; nt++)
#pragma unroll
      for (int r = 0; r < 4; r++) {
        float e = __expf(s_acc[mt][nt][r] - fmx[mt][r]);
        s_acc[mt][nt][r] = e;
        rs[mt][r] += e;
      }
#pragma unroll
  for (int off = 1; off < 16; off <<= 1)
#pragma unroll
    for (int mt = 0; mt < 4; mt++)
#pragma unroll
      for (int r = 0; r < 4; r++) rs[mt][r] += __shfl_xor(rs[mt][r], off);
  if (fm == 0)
#pragma unroll
    for (int mt = 0; mt < 4; mt++)
#pragma unroll
      for (int r = 0; r < 4; r++)
        reds[w * 64 + mt * 16 + quad * 4 + r] = rs[mt][r];
  __syncthreads();  // also guarantees all K_lds reads done before P overwrites
  float inv[4][4];
#pragma unroll
  for (int mt = 0; mt < 4; mt++)
#pragma unroll
    for (int r = 0; r < 4; r++) {
      int row = mt * 16 + quad * 4 + r;
      inv[mt][r] =
          1.0f / (reds[row] + reds[64 + row] + reds[128 + row] + reds[192 + row]);
    }
  // write P (bf16) into KP_s region with stride VSTR (C layout -> memory)
#pragma unroll
  for (int mt = 0; mt < 4; mt++)
#pragma unroll
    for (int nt = 0; nt < 3; nt++) {
      int col = n0s + nt * 16 + fm;
#pragma unroll
      for (int r = 0; r < 4; r++) {
        int row = mt * 16 + quad * 4 + r;
        KP_s[row * VSTR + col] = f2bf(s_acc[mt][nt][r] * inv[mt][r]);
      }
    }
  __syncthreads();

  // ctx = P @ V ; wave covers dh-cols [w*16, w*16+16)
  const int n0v = w * 16;
  f32x4 o_acc[4];
#pragma unroll
  for (int mt = 0; mt < 4; mt++) o_acc[mt] = (f32x4){0.f, 0.f, 0.f, 0.f};
#pragma unroll
  for (int ks = 0; ks < 6; ks++) {
    bf16x8 bv = *(const bf16x8*)&Vt_s[(n0v + fm) * VSTR + ks * 32 + quad * 8];
#pragma unroll
    for (int mt = 0; mt < 4; mt++) {
      bf16x8 ap = *(const bf16x8*)&KP_s[(mt * 16 + fm) * VSTR + ks * 32 + quad * 8];
      o_acc[mt] = MFMA(ap, bv, o_acc[mt]);
    }
  }
  // write ctx bf16 [B*T, 512]
  const int bb = bh >> 3, h = bh & 7;
#pragma unroll
  for (int mt = 0; mt < 4; mt++)
#pragma unroll
    for (int r = 0; r < 4; r++) {
      int t = q0 + mt * 16 + quad * 4 + r;
      int c = h * 64 + n0v + fm;
      ctx_hi[((size_t)(bb * 2048 + t)) * 512 + c] = f2bf(o_acc[mt][r]);
    }
}

// ---------------------------------------------------------------------------
extern "C" void kernel_launch(void* const* d_in, const int* in_sizes, int n_in,
                              void* d_out, int out_size, void* d_ws, size_t ws_size,
                              hipStream_t stream) {
  const float* x = (const float*)d_in[0];
  const float* w_in = (const float*)d_in[1];
  const float* b_in = (const float*)d_in[2];
  const float* w_out = (const float*)d_in[3];
  const float* b_out = (const float*)d_in[4];
  float* out = (float*)d_out;

  uint8_t* ws = (uint8_t*)d_ws;
  unsigned short* xT_hi = (unsigned short*)(ws + 0);           // 4 MiB
  unsigned short* wih   = (unsigned short*)(ws + 8388608);     // 1.5 MiB
  unsigned short* woh   = (unsigned short*)(ws + 9961472);     // 0.5 MiB
  unsigned short* Qs    = (unsigned short*)(ws + 12582912);    // 4 MiB
  unsigned short* Kk    = (unsigned short*)(ws + 16777216);    // 4 MiB
  unsigned short* VvT   = (unsigned short*)(ws + 20971520);    // 4 MiB [B,H,64,T]
  unsigned short* ctxh  = (unsigned short*)(ws + 25165824);    // 4 MiB

  k_prep<<<dim3(64, 17, 2), 256, 0, stream>>>(x, w_in, w_out, xT_hi, wih, woh);
  k_gemm_qkv<<<768, 256, 0, stream>>>(xT_hi, wih, b_in, Qs, Kk, VvT);
  k_attention<<<dim3(32, 16), 256, 0, stream>>>(Qs, Kk, VvT, ctxh);
  k_gemm_out<<<512, 256, 0, stream>>>(ctxh, woh, b_out, x, out);
}

// Round 8
// 115.136 us; speedup vs baseline: 1.0157x; 1.0157x over previous
//
#include <hip/hip_runtime.h>
#include <stdint.h>

// Encoder: B=2,E=512,T=2048,H=8,dh=64, local window |i-j|<=64
// R8: revert R7's tile/grid perturbation to the measured-best R6 config
//     (QKV 128x128 tile / 384 blocks; out-proj 64x128 / 256 blocks).
//     Both larger (R6) and smaller (R7) staging-ratio points are now
//     measured; R6 is the bracketed optimum. No new experiment.

#define DEVI __device__ __forceinline__

typedef __attribute__((ext_vector_type(8))) short bf16x8;   // 8 bf16 in 4 VGPRs
typedef __attribute__((ext_vector_type(4))) float f32x4;

DEVI unsigned short f2bf(float f) {               // RNE float->bf16
  unsigned u = __float_as_uint(f);
  u += 0x7fffu + ((u >> 16) & 1u);
  return (unsigned short)(u >> 16);
}
DEVI float bf2f(unsigned short h) { return __uint_as_float(((unsigned)h) << 16); }

#define GLL16(gp, lp)                                                          \
  __builtin_amdgcn_global_load_lds(                                            \
      (const __attribute__((address_space(1))) void*)(gp),                     \
      (__attribute__((address_space(3))) void*)(lp), 16, 0, 0)

#define MFMA(a, b, c) __builtin_amdgcn_mfma_f32_16x16x32_bf16((a), (b), (c), 0, 0, 0)

// ---------------------------------------------------------------------------
// K0: blockIdx.y<16: x[B,E,T] fp32 -> xT[B*T,512] bf16 (transpose)
//     blockIdx.y==16: w_in/w_out fp32 -> bf16 hi (128 rider blocks)
__global__ __launch_bounds__(256) void k_prep(
    const float* __restrict__ x, const float* __restrict__ w_in,
    const float* __restrict__ w_out, unsigned short* __restrict__ xh,
    unsigned short* __restrict__ wih, unsigned short* __restrict__ woh) {
  const int tid = threadIdx.x;
  if (blockIdx.y == 16) {  // weight convert rider: 128 blocks x 8192 elems
    int cb = (blockIdx.z << 6) | blockIdx.x;
    const float* src;
    unsigned short* dst;
    int base;
    if (cb < 96) {        // 96*8192 = 786432 = w_in exactly
      src = w_in; dst = wih; base = cb * 8192;
    } else {              // 32*8192 = 262144 = w_out exactly
      src = w_out; dst = woh; base = (cb - 96) * 8192;
    }
#pragma unroll
    for (int k = 0; k < 8; k++) {
      int idx = base + (k * 256 + tid) * 4;
      float4 v = *(const float4*)&src[idx];
      ushort4 o;
      o.x = f2bf(v.x); o.y = f2bf(v.y); o.z = f2bf(v.z); o.w = f2bf(v.w);
      *(ushort4*)&dst[idx] = o;
    }
    return;
  }
  __shared__ float tile[32][33];
  const int b = blockIdx.z, e0 = blockIdx.y * 32, t0 = blockIdx.x * 32;
  const int j = tid & 31, i = tid >> 5;  // i: 0..7
#pragma unroll
  for (int rr = 0; rr < 4; rr++) {
    int e = e0 + i + rr * 8;
    tile[i + rr * 8][j] = x[((size_t)b * 512 + e) * 2048 + t0 + j];  // coalesced t
  }
  __syncthreads();
#pragma unroll
  for (int rr = 0; rr < 4; rr++) {
    int t = t0 + i + rr * 8;
    float v = tile[j][i + rr * 8];
    size_t o = ((size_t)b * 2048 + t) * 512 + e0 + j;  // coalesced e
    xh[o] = f2bf(v);
  }
}

// ---------------------------------------------------------------------------
// QKV GEMM: C[m,n] = sum_k Ah[m,k]*Bh[n,k] + bias[n], 128x128 tile, BK=32.
// Grid: 384 linear, XCD-swizzled. Epilogue: Q(*0.125)/K -> [B,H,T,64] bf16,
// V -> TRANSPOSED [B,H,64,T] bf16 (packed ushort4, 4 consecutive t/thread).
__global__ __launch_bounds__(256) void k_gemm_qkv(
    const unsigned short* __restrict__ Ahg, const unsigned short* __restrict__ Bhg,
    const float* __restrict__ bias, unsigned short* __restrict__ Qs,
    unsigned short* __restrict__ Kks, unsigned short* __restrict__ VvT) {
  const int KD = 512;
  __shared__ __align__(16) unsigned short Ah_s[128 * 32];
  __shared__ __align__(16) unsigned short Bh_s[128 * 32];
  const int tid = threadIdx.x, lane = tid & 63, w = tid >> 6;
  // XCD swizzle: dispatch heuristic xcd = bid%8; 48 blocks/XCD = 4m x 12n slab
  const int bid = blockIdx.x;
  const int xcd = bid & 7, j5 = bid >> 3;
  const int m0 = (xcd * 4 + j5 / 12) * 128, n0 = (j5 % 12) * 128;
  const int wm = (w >> 1) * 64, wn = (w & 1) * 64;

  f32x4 acc[4][4];
#pragma unroll
  for (int i = 0; i < 4; i++)
#pragma unroll
    for (int j = 0; j < 4; j++) acc[i][j] = (f32x4){0.f, 0.f, 0.f, 0.f};

  const int srw = lane >> 2, sc = (lane & 3) * 8;
  const size_t b0 = (size_t)(n0 + w * 32 + srw) * KD + sc;
  const size_t b1 = b0 + (size_t)16 * KD;
  unsigned short* lB0 = &Bh_s[(w * 32) * 32];
  unsigned short* lB1 = &Bh_s[(w * 32 + 16) * 32];
  const size_t a0 = (size_t)(m0 + w * 32 + srw) * KD + sc;
  const size_t a1 = a0 + (size_t)16 * KD;
  unsigned short* lAh0 = &Ah_s[(w * 32) * 32];
  unsigned short* lAh1 = &Ah_s[(w * 32 + 16) * 32];

  const int fm = lane & 15, fq = (lane >> 4) * 8;

  for (int k0 = 0; k0 < KD; k0 += 32) {
    __syncthreads();
    GLL16(Ahg + a0 + k0, lAh0);
    GLL16(Ahg + a1 + k0, lAh1);
    GLL16(Bhg + b0 + k0, lB0);
    GLL16(Bhg + b1 + k0, lB1);
    __builtin_amdgcn_s_waitcnt(0);
    __syncthreads();

    bf16x8 ah[4], bh[4];
#pragma unroll
    for (int i = 0; i < 4; i++) {
      ah[i] = *(const bf16x8*)&Ah_s[(wm + i * 16 + fm) * 32 + fq];
      bh[i] = *(const bf16x8*)&Bh_s[(wn + i * 16 + fm) * 32 + fq];
    }
#pragma unroll
    for (int i = 0; i < 4; i++)
#pragma unroll
      for (int j = 0; j < 4; j++)
        acc[i][j] = MFMA(ah[i], bh[j], acc[i][j]);
  }

  // epilogue: C/D layout col=lane&15, row=quad*4+r  [m89-verified]
  const int quad = lane >> 4;
#pragma unroll
  for (int i = 0; i < 4; i++)
#pragma unroll
    for (int j = 0; j < 4; j++) {
      int gn = n0 + wn + j * 16 + fm;
      float bv = bias[gn];
      int sec = gn >> 9, cc = gn & 511;
      int h = cc >> 6, d = cc & 63;
      int gm0 = m0 + wm + i * 16 + quad * 4;       // 4-aligned t base
      int bb = gm0 >> 11, t = gm0 & 2047;
      if (sec == 2) {  // V^T [B,H,64,2048]: 4 consecutive t -> one 8B store
        ushort4 pk;
        pk.x = f2bf(acc[i][j][0] + bv);
        pk.y = f2bf(acc[i][j][1] + bv);
        pk.z = f2bf(acc[i][j][2] + bv);
        pk.w = f2bf(acc[i][j][3] + bv);
        *(ushort4*)&VvT[(((size_t)(bb * 8 + h)) * 64 + d) * 2048 + t] = pk;
      } else {
        unsigned short* dst = sec == 0 ? Qs : Kks;
        float mul = sec == 0 ? 0.125f : 1.0f;  // 1/sqrt(64), exact
#pragma unroll
        for (int r = 0; r < 4; r++) {
          float v = (acc[i][j][r] + bv) * mul;
          dst[(((size_t)(bb * 8 + h)) * 2048 + t + r) * 64 + d] = f2bf(v);
        }
      }
    }
}

// ---------------------------------------------------------------------------
// Out-proj GEMM fused with final transpose * x + relu. Single-pass bf16.
// C[m,n] = sum_k Ah[m,k]*Bh[n,k] + bias[n]; tile 64m x 128n, grid 256.
// Epilogue: LDS transpose -> out[b,e,t] = relu(C[b,t,e] * x[b,e,t]).
__global__ __launch_bounds__(256) void k_gemm_out(
    const unsigned short* __restrict__ Ahg, const unsigned short* __restrict__ Bhg,
    const float* __restrict__ bias, const float* __restrict__ x,
    float* __restrict__ out) {
  const int KD = 512;
  __shared__ __align__(16) union {
    struct {
      unsigned short Ah[64 * 32];
      unsigned short Bh[128 * 32];
    } st;                       // 12 KB staging
    float tile[64][129];        // 32.25 KB epilogue transpose
  } u;
  const int tid = threadIdx.x, lane = tid & 63, w = tid >> 6;
  // XCD swizzle: 32 blocks/XCD = 8m x 4n slab (A 0.5 MB + B 0.5 MB in L2)
  const int bid = blockIdx.x;
  const int xcd = bid & 7, j5 = bid >> 3;
  const int m0 = (xcd * 8 + (j5 >> 2)) * 64, n0 = (j5 & 3) * 128;
  const int wm = (w >> 1) * 32, wn = (w & 1) * 64;

  f32x4 acc[2][4];
#pragma unroll
  for (int i = 0; i < 2; i++)
#pragma unroll
    for (int j = 0; j < 4; j++) acc[i][j] = (f32x4){0.f, 0.f, 0.f, 0.f};

  const int srw = lane >> 2, sc = (lane & 3) * 8;
  const size_t b0 = (size_t)(n0 + w * 32 + srw) * KD + sc;
  const size_t b1 = b0 + (size_t)16 * KD;
  const size_t a0 = (size_t)(m0 + w * 16 + srw) * KD + sc;
  unsigned short* lB0 = &u.st.Bh[(w * 32) * 32];
  unsigned short* lB1 = &u.st.Bh[(w * 32 + 16) * 32];
  unsigned short* lAh0 = &u.st.Ah[(w * 16) * 32];

  const int fm = lane & 15, fq = (lane >> 4) * 8;

  for (int k0 = 0; k0 < KD; k0 += 32) {
    __syncthreads();
    GLL16(Ahg + a0 + k0, lAh0);
    GLL16(Bhg + b0 + k0, lB0);
    GLL16(Bhg + b1 + k0, lB1);
    __builtin_amdgcn_s_waitcnt(0);
    __syncthreads();

    bf16x8 ah[2], bh[4];
#pragma unroll
    for (int i = 0; i < 2; i++)
      ah[i] = *(const bf16x8*)&u.st.Ah[(wm + i * 16 + fm) * 32 + fq];
#pragma unroll
    for (int j = 0; j < 4; j++)
      bh[j] = *(const bf16x8*)&u.st.Bh[(wn + j * 16 + fm) * 32 + fq];
#pragma unroll
    for (int i = 0; i < 2; i++)
#pragma unroll
      for (int j = 0; j < 4; j++)
        acc[i][j] = MFMA(ah[i], bh[j], acc[i][j]);
  }

  __syncthreads();  // all frag reads done before tile overwrites staging
  // write acc+bias into transpose tile: tile[t_local][e_local]
  const int quad = lane >> 4;
#pragma unroll
  for (int i = 0; i < 2; i++)
#pragma unroll
    for (int j = 0; j < 4; j++) {
      int ln = wn + j * 16 + fm;
      float bv = bias[n0 + ln];
#pragma unroll
      for (int r = 0; r < 4; r++) {
        int lm = wm + i * 16 + quad * 4 + r;
        u.tile[lm][ln] = acc[i][j][r] + bv;
      }
    }
  __syncthreads();

  // out[b,e,t] = relu(tile[t][e] * x[b,e,t]); coalesced along t
  const int bb = m0 >> 11, t0 = m0 & 2047;
  const int tt = tid & 63, e0w = tid >> 6;
#pragma unroll
  for (int k = 0; k < 32; k++) {
    int ee = e0w + k * 4;
    size_t o = ((size_t)bb * 512 + n0 + ee) * 2048 + t0 + tt;
    float v = u.tile[tt][ee] * x[o];
    out[o] = fmaxf(v, 0.f);
  }
}

// ---------------------------------------------------------------------------
// K2: local attention. Block = (b,h, 64 queries). Window = 192 keys.
// V arrives already transposed in global [B,H,64,2048].
#define KSTR 88   // K_lds row stride (bf16): 176B, 2-way-free b128 reads
#define VSTR 216  // Vt/P row stride (bf16): 432B, 2-way-free b128 reads
__global__ __launch_bounds__(256) void k_attention(
    const unsigned short* __restrict__ Qs, const unsigned short* __restrict__ Kks,
    const unsigned short* __restrict__ VvT, unsigned short* __restrict__ ctx_hi) {
  __shared__ __align__(16) unsigned short KP_s[192 * KSTR];  // K, later P (64 x VSTR)
  __shared__ __align__(16) unsigned short Vt_s[64 * VSTR];   // V^T [dh][key]
  __shared__ float redm[4 * 64];
  __shared__ float reds[4 * 64];

  const int tid = threadIdx.x, lane = tid & 63, w = tid >> 6;
  const int q0 = blockIdx.x * 64;
  const int bh = blockIdx.y;
  const int j0 = q0 - 64;
  const size_t base = (size_t)bh * 2048 * 64;

  // stage K rows (clamped; garbage rows are masked before softmax)
  for (int idx = tid; idx < 192 * 8; idx += 256) {
    int r = idx >> 3, c = idx & 7;
    int j = j0 + r;
    j = j < 0 ? 0 : (j > 2047 ? 2047 : j);
    uint4 v = *(const uint4*)&Kks[base + (size_t)j * 64 + c * 8];
    *(uint4*)&KP_s[r * KSTR + c * 8] = v;
  }
  // stage V^T rows: pure uint4 copies (j0 and chunk starts 8-aligned -> a
  // chunk is never OOB-straddling; OOB chunks fully zero)
  for (int idx = tid; idx < 64 * 24; idx += 256) {
    int d = idx / 24, c8 = (idx % 24) * 8;
    int j = j0 + c8;
    uint4 v;
    if (j >= 0 && j < 2048)
      v = *(const uint4*)&VvT[base + (size_t)d * 2048 + j];
    else
      v = (uint4){0u, 0u, 0u, 0u};  // OOB keys ZERO (0*garbage hazard)
    *(uint4*)&Vt_s[d * VSTR + c8] = v;
  }

  // Q fragments straight from global (A layout: m=lane&15, k=quad*8+j)
  const int fm = lane & 15, quad = lane >> 4;
  bf16x8 aq[4][2];
#pragma unroll
  for (int mt = 0; mt < 4; mt++)
#pragma unroll
    for (int ks = 0; ks < 2; ks++)
      aq[mt][ks] = *(const bf16x8*)&Qs[base + (size_t)(q0 + mt * 16 + fm) * 64 +
                                       ks * 32 + quad * 8];
  __syncthreads();

  // S = Qs @ K^T ; wave covers key-cols [w*48, w*48+48)
  const int n0s = w * 48;
  f32x4 s_acc[4][3];
#pragma unroll
  for (int mt = 0; mt < 4; mt++)
#pragma unroll
    for (int nt = 0; nt < 3; nt++) s_acc[mt][nt] = (f32x4){0.f, 0.f, 0.f, 0.f};
#pragma unroll
  for (int nt = 0; nt < 3; nt++)
#pragma unroll
    for (int ks = 0; ks < 2; ks++) {
      bf16x8 bk =
          *(const bf16x8*)&KP_s[(n0s + nt * 16 + fm) * KSTR + ks * 32 + quad * 8];
#pragma unroll
      for (int mt = 0; mt < 4; mt++) s_acc[mt][nt] = MFMA(aq[mt][ks], bk, s_acc[mt][nt]);
    }

  // mask (REPLACE, not add) + per-row max
  float rm[4][4];
#pragma unroll
  for (int mt = 0; mt < 4; mt++)
#pragma unroll
    for (int r = 0; r < 4; r++) rm[mt][r] = -1e30f;
#pragma unroll
  for (int mt = 0; mt < 4; mt++)
#pragma unroll
    for (int nt = 0; nt < 3; nt++) {
      int jj = n0s + nt * 16 + fm;
      int jg = j0 + jj;
#pragma unroll
      for (int r = 0; r < 4; r++) {
        int ii = mt * 16 + quad * 4 + r;
        bool ok = (jj >= ii) && (jj <= ii + 128) && (jg >= 0) && (jg < 2048);
        float sv = ok ? s_acc[mt][nt][r] : -1e30f;
        s_acc[mt][nt][r] = sv;
        rm[mt][r] = fmaxf(rm[mt][r], sv);
      }
    }
  // reduce max over the 16-lane col group, then cross-wave via LDS
#pragma unroll
  for (int off = 1; off < 16; off <<= 1)
#pragma unroll
    for (int mt = 0; mt < 4; mt++)
#pragma unroll
      for (int r = 0; r < 4; r++)
        rm[mt][r] = fmaxf(rm[mt][r], __shfl_xor(rm[mt][r], off));
  if (fm == 0)
#pragma unroll
    for (int mt = 0; mt < 4; mt++)
#pragma unroll
      for (int r = 0; r < 4; r++)
        redm[w * 64 + mt * 16 + quad * 4 + r] = rm[mt][r];
  __syncthreads();
  float fmx[4][4];
#pragma unroll
  for (int mt = 0; mt < 4; mt++)
#pragma unroll
    for (int r = 0; r < 4; r++) {
      int row = mt * 16 + quad * 4 + r;
      fmx[mt][r] = fmaxf(fmaxf(redm[row], redm[64 + row]),
                         fmaxf(redm[128 + row], redm[192 + row]));
    }
  // exp + row sum (masked entries underflow to exactly 0)
  float rs[4][4];
#pragma unroll
  for (int mt = 0; mt < 4; mt++)
#pragma unroll
    for (int r = 0; r < 4; r++) rs[mt][r] = 0.f;
#pragma unroll
  for (int mt = 0; mt < 4; mt++)
#pragma unroll
    for (int nt = 0; nt < 3; nt++)
#pragma unroll
      for (int r = 0; r < 4; r++) {
        float e = __expf(s_acc[mt][nt][r] - fmx[mt][r]);
        s_acc[mt][nt][r] = e;
        rs[mt][r] += e;
      }
#pragma unroll
  for (int off = 1; off < 16; off <<= 1)
#pragma unroll
    for (int mt = 0; mt < 4; mt++)
#pragma unroll
      for (int r = 0; r < 4; r++) rs[mt][r] += __shfl_xor(rs[mt][r], off);
  if (fm == 0)
#pragma unroll
    for (int mt = 0; mt < 4; mt++)
#pragma unroll
      for (int r = 0; r < 4; r++)
        reds[w * 64 + mt * 16 + quad * 4 + r] = rs[mt][r];
  __syncthreads();  // also guarantees all K_lds reads done before P overwrites
  float inv[4][4];
#pragma unroll
  for (int mt = 0; mt < 4; mt++)
#pragma unroll
    for (int r = 0; r < 4; r++) {
      int row = mt * 16 + quad * 4 + r;
      inv[mt][r] =
          1.0f / (reds[row] + reds[64 + row] + reds[128 + row] + reds[192 + row]);
    }
  // write P (bf16) into KP_s region with stride VSTR (C layout -> memory)
#pragma unroll
  for (int mt = 0; mt < 4; mt++)
#pragma unroll
    for (int nt = 0; nt < 3; nt++) {
      int col = n0s + nt * 16 + fm;
#pragma unroll
      for (int r = 0; r < 4; r++) {
        int row = mt * 16 + quad * 4 + r;
        KP_s[row * VSTR + col] = f2bf(s_acc[mt][nt][r] * inv[mt][r]);
      }
    }
  __syncthreads();

  // ctx = P @ V ; wave covers dh-cols [w*16, w*16+16)
  const int n0v = w * 16;
  f32x4 o_acc[4];
#pragma unroll
  for (int mt = 0; mt < 4; mt++) o_acc[mt] = (f32x4){0.f, 0.f, 0.f, 0.f};
#pragma unroll
  for (int ks = 0; ks < 6; ks++) {
    bf16x8 bv = *(const bf16x8*)&Vt_s[(n0v + fm) * VSTR + ks * 32 + quad * 8];
#pragma unroll
    for (int mt = 0; mt < 4; mt++) {
      bf16x8 ap = *(const bf16x8*)&KP_s[(mt * 16 + fm) * VSTR + ks * 32 + quad * 8];
      o_acc[mt] = MFMA(ap, bv, o_acc[mt]);
    }
  }
  // write ctx bf16 [B*T, 512]
  const int bb = bh >> 3, h = bh & 7;
#pragma unroll
  for (int mt = 0; mt < 4; mt++)
#pragma unroll
    for (int r = 0; r < 4; r++) {
      int t = q0 + mt * 16 + quad * 4 + r;
      int c = h * 64 + n0v + fm;
      ctx_hi[((size_t)(bb * 2048 + t)) * 512 + c] = f2bf(o_acc[mt][r]);
    }
}

// ---------------------------------------------------------------------------
extern "C" void kernel_launch(void* const* d_in, const int* in_sizes, int n_in,
                              void* d_out, int out_size, void* d_ws, size_t ws_size,
                              hipStream_t stream) {
  const float* x = (const float*)d_in[0];
  const float* w_in = (const float*)d_in[1];
  const float* b_in = (const float*)d_in[2];
  const float* w_out = (const float*)d_in[3];
  const float* b_out = (const float*)d_in[4];
  float* out = (float*)d_out;

  uint8_t* ws = (uint8_t*)d_ws;
  unsigned short* xT_hi = (unsigned short*)(ws + 0);           // 4 MiB
  unsigned short* wih   = (unsigned short*)(ws + 8388608);     // 1.5 MiB
  unsigned short* woh   = (unsigned short*)(ws + 9961472);     // 0.5 MiB
  unsigned short* Qs    = (unsigned short*)(ws + 12582912);    // 4 MiB
  unsigned short* Kk    = (unsigned short*)(ws + 16777216);    // 4 MiB
  unsigned short* VvT   = (unsigned short*)(ws + 20971520);    // 4 MiB [B,H,64,T]
  unsigned short* ctxh  = (unsigned short*)(ws + 25165824);    // 4 MiB

  k_prep<<<dim3(64, 17, 2), 256, 0, stream>>>(x, w_in, w_out, xT_hi, wih, woh);
  k_gemm_qkv<<<384, 256, 0, stream>>>(xT_hi, wih, b_in, Qs, Kk, VvT);
  k_attention<<<dim3(32, 16), 256, 0, stream>>>(Qs, Kk, VvT, ctxh);
  k_gemm_out<<<256, 256, 0, stream>>>(ctxh, woh, b_out, x, out);
}